// Round 8
// baseline (211.482 us; speedup 1.0000x reference)
//
#include <hip/hip_runtime.h>

// Dilate = 5x5 per-channel max filter, SAME padding, (64,384,384,3) f32.
// v8 = v7's verified DMA machinery with DEEP pipeline: ring 8->16 rows.
//   Unified theory of v1-v7 (all ~72-76 us): sustained BW = in-flight
//   bytes / latency. Every prior variant held <=~15-20 KB/CU in flight
//   (compiler collapsed VGPR windows to depth 1-2; v7's 8-row ring capped
//   depth at 3 stages/wave, barrier phase-locked) -> 2.3-2.6 TB/s. The
//   BW.latency product at 6.3 TB/s x ~900 ns needs ~22+ KB/CU sustained.
//   This version: 16-row LDS ring (73,728 B), stage depth 15 (steady 11
//   outstanding stages/wave = 11 KB); 2 blocks/CU x 5 waves -> ~110 KB/CU
//   in flight. vmcnt at round k gates a stage issued 11 rounds ago ->
//   waits are slack; stages free-stream ahead of the barrier cadence.
//   - block = 320 thr (5 waves) owns a 48-row band; 512 blocks = 2/CU
//     exactly, one generation, halo overfetch 52/48 = 1.083x
//   - per round: [stage row k+15 (k<=36)] | vmcnt(NW(k)) | bar |
//     compute row k from ring slots (k..k+4)&15 | bar
//   - NW(k) from per-wave FIFO (1 stage + 1 store per round), derived
//     entry-by-entry: k<=36: 11+min(k,11); k>=37: 58-k. Max 22 < 63.
//   - compute path verbatim from v5/v7 (absmax 0.0): per-wave 60-col strip,
//     +-2 lane halo, vert5 from own LDS column, 12-shuffle horizontal.
//   - raw s_barrier (NOT __syncthreads - would drain vmcnt(0)).
//   grid = 64 img x 8 bands = 512 (divisible by 8 -> XCD swizzle exact).

#define Bn 64
#define H 384
#define ROWB 4608            // bytes per image row (384*3*4)
#define WF4 288              // float4 words per row
#define RB 48                // output rows per block
#define NIN (RB + 4)         // 52 input rows incl halo
#define BANDS (H / RB)       // 8
#define NBLK (Bn * BANDS)    // 512 (divisible by 8)
#define NTHR 320
#define RING 16              // LDS ring rows (73,728 B)
#define DEPTH 15             // prologue stages; steady outstanding = 11
#define NEGINF (-3.402823466e+38f)

typedef float f32x4 __attribute__((ext_vector_type(4)));

template <int I> struct Ic { static constexpr int v = I; };
template <int I, int N, class F>
__device__ __forceinline__ void static_for(F f) {
  if constexpr (I < N) {
    f(Ic<I>{});
    static_for<I + 1, N>(f);
  }
}

// Counted vmcnt wait, fenced both sides (rule #18).
template <int N>
__device__ __forceinline__ void vm_wait() {
  __builtin_amdgcn_sched_barrier(0);
  asm volatile("s_waitcnt vmcnt(%0)" ::"n"(N) : "memory");
  __builtin_amdgcn_sched_barrier(0);
}

// Per-wave FIFO wait count before consuming rows k..k+4.
// Round j issues stage(j+15) (j<=36) then store(j); prologue = stages 0..14.
// Entries newer than stage(k+4):
//   k<=36: 11 stages + min(k,11) stores = 11+min(k,11)
//   k>=37: (47-k) stages + 11 stores = 58-k
__host__ __device__ constexpr int NW(int k) {
  return k <= 36 ? 11 + (k < 11 ? k : 11) : 58 - k;
}

__device__ __forceinline__ f32x4 max4(f32x4 a, f32x4 b) {
  f32x4 r;
  r.x = fmaxf(a.x, b.x); r.y = fmaxf(a.y, b.y);
  r.z = fmaxf(a.z, b.z); r.w = fmaxf(a.w, b.w);
  return r;
}

__global__ __launch_bounds__(NTHR, 2) void dilate5_kernel(
    const float* __restrict__ in, float* __restrict__ out) {
  __shared__ f32x4 ring[RING][WF4];            // 16 x 4608 B = 73,728 B

  const int t = threadIdx.x;
  const int wv = t >> 6;
  const int lane = t & 63;

  // XCD swizzle: XCD x owns 8 consecutive images (verified FETCH win).
  const int orig = blockIdx.x;
  const int q = (orig & 7) * (NBLK / 8) + (orig >> 3);
  const int band = q % BANDS;
  const int b = q / BANDS;
  const int r0 = band * RB;

  const char* __restrict__ imgb = (const char*)in + (size_t)b * H * ROWB;
  char* __restrict__ outb = (char*)out + (size_t)b * H * ROWB;

  // ---- staging: every wave issues EXACTLY 1 global_load_lds per row ----
  const int soff = wv * 1024 + lane * 16;      // byte offset within a row
  const bool sact = soff < ROWB;               // wave 4: lanes 0..31 only
  char* lds0 = (char*)&ring[0][0];

  auto stage = [&](int j) {                    // input row index 0..NIN-1
    int gh = r0 - 2 + j;
    gh = gh < 0 ? 0 : (gh > H - 1 ? H - 1 : gh);   // vertical SAME padding
    const char* src = imgb + (size_t)gh * ROWB + soff;
    char* dst = lds0 + (size_t)(j & (RING - 1)) * ROWB + soff;
    if (sact)
      __builtin_amdgcn_global_load_lds(
          (const __attribute__((address_space(1))) void*)src,
          (__attribute__((address_space(3))) void*)dst, 16, 0, 0);
  };

  // ---- compute geometry (v5/v7-verified): wave wv owns 60-col strip with
  // +-2 lane halo; col may be OOB -> -inf via cvalid. ----
  const int col = wv * 60 - 2 + lane;
  const bool cvalid = (col >= 0) && (col < WF4);
  const int ccl = col < 0 ? 0 : (col > WF4 - 1 ? WF4 - 1 : col);
  const bool willstore = (lane >= 2) && (lane < 62) && (col < WF4);

  // ---- prologue: stage rows 0..14 (15 KB in flight per wave) ----
#pragma unroll
  for (int j = 0; j < DEPTH; ++j) stage(j);

  // ---- 48 rounds: [stage k+15] | vmcnt(NW(k)) | bar | compute k | bar ----
  static_for<0, RB>([&](auto ic) {
    constexpr int k = decltype(ic)::v;
    if constexpr (k + DEPTH < NIN) stage(k + DEPTH);
    vm_wait<NW(k)>();
    __builtin_amdgcn_s_barrier();

    // vertical 5-max from LDS ring, own column (5x ds_read_b128)
    f32x4 v = max4(
        max4(max4(ring[(k + 0) & (RING - 1)][ccl],
                  ring[(k + 1) & (RING - 1)][ccl]),
             max4(ring[(k + 2) & (RING - 1)][ccl],
                  ring[(k + 3) & (RING - 1)][ccl])),
        ring[(k + 4) & (RING - 1)][ccl]);
    if (!cvalid) { v.x = NEGINF; v.y = NEGINF; v.z = NEGINF; v.w = NEGINF; }

    // horizontal 5-max, channel stride 3 (verified formulas):
    // word c-2 contributes only .z/.w, word c+2 only .x/.y -> 12 shuffles.
    float Bx = __shfl_up(v.x, 1), By = __shfl_up(v.y, 1);
    float Bz = __shfl_up(v.z, 1), Bw = __shfl_up(v.w, 1);
    float Dx = __shfl_down(v.x, 1), Dy = __shfl_down(v.y, 1);
    float Dz = __shfl_down(v.z, 1), Dw = __shfl_down(v.w, 1);
    float Az = __shfl_up(v.z, 2), Aw = __shfl_up(v.w, 2);
    float Ex = __shfl_down(v.x, 2), Ey = __shfl_down(v.y, 2);
    f32x4 h;
    h.x = fmaxf(fmaxf(fmaxf(Az, By), fmaxf(v.x, v.w)), Dz);
    h.y = fmaxf(fmaxf(fmaxf(Aw, Bz), fmaxf(v.y, Dx)), Dw);
    h.z = fmaxf(fmaxf(fmaxf(Bx, Bw), fmaxf(v.z, Dy)), Ex);
    h.w = fmaxf(fmaxf(fmaxf(By, v.x), fmaxf(v.w, Dz)), Ey);

    if (willstore)
      *reinterpret_cast<f32x4*>(outb + (size_t)(r0 + k) * ROWB +
                                (size_t)col * 16) = h;

    __builtin_amdgcn_s_barrier();   // slot reuse: stage(k+16) next round
  });
}

extern "C" void kernel_launch(void* const* d_in, const int* in_sizes, int n_in,
                              void* d_out, int out_size, void* d_ws, size_t ws_size,
                              hipStream_t stream) {
  const float* images = (const float*)d_in[0];
  float* out = (float*)d_out;
  dilate5_kernel<<<NBLK, NTHR, 0, stream>>>(images, out);
}